// Round 6
// baseline (359.655 us; speedup 1.0000x reference)
//
#include <hip/hip_runtime.h>
#include <hip/hip_fp16.h>
#include <cmath>

#define BATCH 16
#define NID   15
#define NSEG  240
#define HW    262144          // 512*512
#define HEADB 65536
#define NSPL  8               // hist blocks per segment
#define S1T   512             // hist block threads
#define PREBLK 4096           // pre blocks (256 per batch, 1024 px each)
#define PSTRIDE 112           // floats per pre-block partial record (105 stats + 1 bg + pad)

// compact key space for d = exp(-arg) in [0,1]:
//   d >= 2^-8 : fine buckets (float_bits>>15), 2305 keys, ~0.39% relative width
//   d <  2^-8 : exponent-only buckets (float_bits>>23), 119 keys
#define KFINEBASE 30208       // 0x3B800000 >> 15
#define KOVF 119
#define KTOT 2424             // 119 + 2305

__device__ __forceinline__ int keyof(float d) {
  unsigned b = __float_as_uint(d);
  return (b >= 0x3B800000u) ? (int)((b >> 15) - KFINEBASE + KOVF) : (int)(b >> 23);
}
__device__ __forceinline__ void boundsof(int k, float* lo, float* hi) {
  if (k >= KOVF) {
    unsigned u = (unsigned)(k - KOVF + KFINEBASE) << 15;
    *lo = __uint_as_float(u);
    *hi = __uint_as_float(u + 32768u);
  } else {
    *lo = __uint_as_float((unsigned)k << 23);
    *hi = __uint_as_float((unsigned)(k + 1) << 23);
  }
}

struct Params { float cx, cy, e0, e1, var, valid, cnt; };
__device__ __forceinline__ Params calc_params(const float* __restrict__ st) {
  Params p;
  float cnt = st[0];
  float safe = fmaxf(cnt, 1.0f);
  p.cx = st[1] / safe;
  p.cy = st[2] / safe;
  float m0 = st[3] / safe, m1 = st[4] / safe;
  float v0 = st[5] - 2.0f * m0 * (m0 * safe) + m0 * m0 * cnt;
  float v1 = st[6] - 2.0f * m1 * (m1 * safe) + m1 * m1 * cnt;
  p.var = (v0 + v1) / (2.0f * safe);
  p.e0 = expf(10.0f * m0);
  p.e1 = expf(10.0f * m1);
  p.valid = (cnt > 0.f) ? 1.f : 0.f;
  p.cnt = cnt;
  return p;
}

// ---------------- pre: vectorized transform + 8-way privatized LDS stats + packed records ----------------
__global__ void __launch_bounds__(256)
pre_kernel(const float* __restrict__ pred, const int* __restrict__ inst,
           const int* __restrict__ lab, float* __restrict__ blockpart,
           unsigned* __restrict__ exyh, unsigned* __restrict__ tb8,
           unsigned* __restrict__ sd8) {
  __shared__ float ls[4][8][NID * 7];   // per-wave, 8-way lane-privatized
  __shared__ float lbg[4];
  int tid = threadIdx.x;
  int w = tid >> 6, lane = tid & 63, c8 = lane & 7;
  for (int i = tid; i < 4 * 8 * NID * 7; i += 256) ((float*)ls)[i] = 0.f;
  __syncthreads();
  int gid = blockIdx.x;
  int b = gid >> 8, c = gid & 255;     // 256 blocks per batch, 1024 px per block
  const float* pb = pred + (size_t)b * 5 * HW;
  int i4 = c * 256 + tid;              // float4 index within batch
  float4 v0 = ((const float4*)pb)[i4];
  float4 v1 = ((const float4*)(pb + HW))[i4];
  float4 v2 = ((const float4*)(pb + 2 * HW))[i4];
  float4 v3 = ((const float4*)(pb + 3 * HW))[i4];
  float4 v4 = ((const float4*)(pb + 4 * HW))[i4];
  int4 t4 = ((const int4*)(inst + (size_t)b * HW))[i4];
  int4 l4 = ((const int4*)(lab + (size_t)b * HW))[i4];
  int px0 = i4 * 4;
  float bgacc = 0.f;
  unsigned eo[4], tpack = 0, spack = 0;
  float p0a[4] = {v0.x, v0.y, v0.z, v0.w};
  float p1a[4] = {v1.x, v1.y, v1.z, v1.w};
  float p2a[4] = {v2.x, v2.y, v2.z, v2.w};
  float p3a[4] = {v3.x, v3.y, v3.z, v3.w};
  float p4a[4] = {v4.x, v4.y, v4.z, v4.w};
  int ta[4] = {t4.x, t4.y, t4.z, t4.w};
  int la[4] = {l4.x, l4.y, l4.z, l4.w};
#pragma unroll
  for (int k = 0; k < 4; ++k) {
    int px = px0 + k;
    float xm = (float)(px & 511) * (1.0f / 511.0f);
    float ym = (float)(px >> 9) * (1.0f / 511.0f);
    float ex = tanhf(p0a[k]) + xm;
    float ey = tanhf(p1a[k]) + ym;
    float sd = 1.0f / (1.0f + expf(-p4a[k]));
    __half2 h = __floats2half2_rn(ex, ey);
    eo[k] = *reinterpret_cast<unsigned*>(&h);
    int t = ta[k];
    tpack |= ((unsigned)(t & 255)) << (8 * k);
    unsigned sq = (unsigned)(sd * 255.0f + 0.5f);
    spack |= (sq & 255u) << (8 * k);
    if (t >= 1 && t <= NID) {
      float* s = ls[w][c8] + (t - 1) * 7;
      atomicAdd(s + 0, 1.0f);
      atomicAdd(s + 1, ex);
      atomicAdd(s + 2, ey);
      atomicAdd(s + 3, p2a[k]);
      atomicAdd(s + 4, p3a[k]);
      atomicAdd(s + 5, p2a[k] * p2a[k]);
      atomicAdd(s + 6, p3a[k] * p3a[k]);
    }
    if (la[k] == 0) bgacc += sd * sd;
  }
  ((uint4*)exyh)[(size_t)b * (HW / 16) + i4] = make_uint4(eo[0], eo[1], eo[2], eo[3]);
  tb8[(size_t)b * (HW / 4) + i4] = tpack;
  sd8[(size_t)b * (HW / 4) + i4] = spack;
  for (int off = 32; off > 0; off >>= 1) bgacc += __shfl_down(bgacc, off, 64);
  if (lane == 0) lbg[w] = bgacc;
  __syncthreads();
  float* bp = blockpart + (size_t)gid * PSTRIDE;
  for (int i = tid; i < NID * 7; i += 256) {
    float v = 0.f;
#pragma unroll
    for (int ww = 0; ww < 4; ++ww)
#pragma unroll
      for (int cc = 0; cc < 8; ++cc) v += ls[ww][cc][i];
    bp[i] = v;
  }
  if (tid == 0) bp[NID * 7] = lbg[0] + lbg[1] + lbg[2] + lbg[3];
}

// ---------------- reduce pre partials -> stats, seedbg ----------------
__global__ void reduce_kernel(const float* __restrict__ blockpart, float* __restrict__ stats,
                              float* __restrict__ seedbg) {
  int s = blockIdx.x;       // 0..105
  int b = blockIdx.y;
  int tid = threadIdx.x;    // 256 = blocks per batch
  float v = blockpart[(size_t)(b * 256 + tid) * PSTRIDE + s];
  for (int off = 32; off > 0; off >>= 1) v += __shfl_down(v, off, 64);
  __shared__ float red[4];
  if ((tid & 63) == 0) red[tid >> 6] = v;
  __syncthreads();
  if (tid == 0) {
    float tot = red[0] + red[1] + red[2] + red[3];
    if (s < NID * 7) {
      int id = s / 7, st = s % 7;
      stats[(b * NID + id) * 8 + st] = tot;
    } else {
      seedbg[b] = tot;
    }
  }
}

// ---------------- phase 1: split per-segment LDS histograms from packed records ----------------
__global__ void __launch_bounds__(S1T)
hist_kernel(const unsigned* __restrict__ exyh, const unsigned* __restrict__ tb8,
            const unsigned* __restrict__ sd8, const float* __restrict__ stats,
            unsigned short* __restrict__ partP, unsigned short* __restrict__ partN,
            float* __restrict__ seedi) {
  int bid = blockIdx.x;
  int seg = bid / NSPL, split = bid % NSPL;
  int b = seg / NID, n = seg % NID;
  __shared__ int histP[KTOT];
  __shared__ int histN[KTOT];
  __shared__ float prm[8];
  int tid = threadIdx.x;
  if (tid == 0) {
    Params pp = calc_params(stats + (size_t)seg * 8);
    prm[0] = pp.cx; prm[1] = pp.cy; prm[2] = pp.e0; prm[3] = pp.e1;
    prm[4] = pp.valid;
  }
  for (int k = tid; k < KTOT; k += S1T) { histP[k] = 0; histN[k] = 0; }
  __syncthreads();
  if (prm[4] == 0.f) return;   // invalid segment: partials never read
  float cx = prm[0], cy = prm[1], e0 = prm[2], e1 = prm[3];
  const uint4* ev = (const uint4*)exyh + (size_t)b * (HW / 16);
  const unsigned* tv = tb8 + (size_t)b * (HW / 4);
  const unsigned* sv = sd8 + (size_t)b * (HW / 4);
  int lane = tid & 63;
  int wid = tid >> 6;               // 8 waves
  int swl = (lane * 21) & 63;       // decorrelate bucket keys within a wave
  float sacc = 0.f;
  // 4-px groups: HW/4 = 65536 per batch; per split 8192; per block 16 iters of 512
  for (int it = 0; it < 16; ++it) {
    int g = split * 8192 + it * 512 + wid * 64 + swl;    // 4-px group index
    unsigned tp = tv[g];
    unsigned sp = sv[g];
    uint4 ee = ev[g];               // 4 px of packed half2 (16 B)
    unsigned ew[4] = {ee.x, ee.y, ee.z, ee.w};
#pragma unroll
    for (int k = 0; k < 4; ++k) {
      unsigned u = ew[k];
      __half2 h = *reinterpret_cast<__half2*>(&u);
      float2 e = __half22float2(h);
      float dx = e.x - cx;
      float dy = e.y - cy;
      float d = expf(-(e0 * dx * dx + e1 * dy * dy));
      int key = keyof(d);
      int t = (int)((tp >> (8 * k)) & 255u);
      if (t == n + 1) {
        atomicAdd(&histP[key], 1);
        float sd = (float)((sp >> (8 * k)) & 255u) * (1.0f / 255.0f);
        float df = sd - d;
        sacc += df * df;
      } else {
        atomicAdd(&histN[key], 1);
      }
    }
  }
  for (int off = 32; off > 0; off >>= 1) sacc += __shfl_down(sacc, off, 64);
  if (lane == 0 && sacc != 0.f) atomicAdd(&seedi[seg], sacc);
  __syncthreads();
  size_t pb = (size_t)bid * KTOT;
  for (int k = tid; k < KTOT; k += S1T) {
    partP[pb + k] = (unsigned short)histP[k];
    partN[pb + k] = (unsigned short)histN[k];
  }
}

// ---------------- phase 2+3: combine partials, LDS scans, bucket-sweep Lovasz ----------------
__global__ void __launch_bounds__(1024)
lovasz_kernel(const unsigned short* __restrict__ partP, const unsigned short* __restrict__ partN,
              const float* __restrict__ stats, float* __restrict__ instAcc) {
  __shared__ int histP[KTOT];
  __shared__ int histN[KTOT];
  __shared__ int PreP[KTOT + 1];
  __shared__ int PreN[KTOT + 1];
  __shared__ int scr[1024];
  __shared__ float prm[2];
  int seg = blockIdx.x;
  int tid = threadIdx.x;
  if (tid == 0) {
    Params pp = calc_params(stats + (size_t)seg * 8);
    prm[0] = pp.valid;
    prm[1] = pp.cnt;
  }
  __syncthreads();
  if (prm[0] == 0.f) {
    if (tid == 0) instAcc[seg] = 0.f;
    return;
  }
  int P = (int)prm[1];
  int Nn = HW - P;
  for (int k = tid; k < KTOT; k += 1024) {
    int sp = 0, sn = 0;
#pragma unroll
    for (int s = 0; s < NSPL; ++s) {
      size_t pb = (size_t)(seg * NSPL + s) * KTOT;
      sp += partP[pb + k];
      sn += partN[pb + k];
    }
    histP[k] = sp;
    histN[k] = sn;
  }
  __syncthreads();
  {
    int base = tid * 3;
    int a0 = (base < KTOT) ? histP[base] : 0;
    int a1 = (base + 1 < KTOT) ? histP[base + 1] : 0;
    int a2 = (base + 2 < KTOT) ? histP[base + 2] : 0;
    scr[tid] = a0 + a1 + a2;
    __syncthreads();
    for (int off = 1; off < 1024; off <<= 1) {
      int v = scr[tid];
      int u = (tid >= off) ? scr[tid - off] : 0;
      __syncthreads();
      scr[tid] = v + u;
      __syncthreads();
    }
    int excl = (tid > 0) ? scr[tid - 1] : 0;
    if (base < KTOT) PreP[base] = excl;
    if (base + 1 < KTOT) PreP[base + 1] = excl + a0;
    if (base + 2 < KTOT) PreP[base + 2] = excl + a0 + a1;
    if (tid == 0) PreP[KTOT] = scr[1023];
    __syncthreads();
    a0 = (base < KTOT) ? histN[base] : 0;
    a1 = (base + 1 < KTOT) ? histN[base + 1] : 0;
    a2 = (base + 2 < KTOT) ? histN[base + 2] : 0;
    scr[tid] = a0 + a1 + a2;
    __syncthreads();
    for (int off = 1; off < 1024; off <<= 1) {
      int v = scr[tid];
      int u = (tid >= off) ? scr[tid - off] : 0;
      __syncthreads();
      scr[tid] = v + u;
      __syncthreads();
    }
    excl = (tid > 0) ? scr[tid - 1] : 0;
    if (base < KTOT) PreN[base] = excl;
    if (base + 1 < KTOT) PreN[base + 1] = excl + a0;
    if (base + 2 < KTOT) PreN[base + 2] = excl + a0 + a1;
    if (tid == 0) PreN[KTOT] = scr[1023];
    __syncthreads();
  }
  float acc = 0.f;
  for (int k = tid; k < KTOT; k += 1024) {
    int hp = histP[k], hn = histN[k];
    if ((hp | hn) == 0) continue;
    float lo, hi;
    boundsof(k, &lo, &hi);
    float m = 0.5f * (lo + hi);
    m = fminf(m, __uint_as_float(0x3F7FFFFFu));
    float tv = 1.0f - m;
    int j = keyof(tv);
    float jlo, jhi;
    boundsof(j, &jlo, &jhi);
    float den = jhi - jlo;
    float fr = (den > 0.f) ? (tv - jlo) / den : 0.5f;
    fr = fminf(fmaxf(fr, 0.f), 1.f);
    if (hp) {
      float q = (float)(Nn - PreN[j + 1]) + (1.0f - fr) * (float)histN[j];
      float a = 2.0f - 2.0f * m;
      acc += (float)hp * a / ((float)P + q);
    }
    if (hn) {
      float p = (float)PreP[j] + fr * (float)histP[j];
      int R = Nn - PreN[k + 1];
      float u0 = 1.0f / (float)(P + R);
      float u1 = 1.0f / (float)(P + R + hn);
      acc += (2.0f * m) * ((float)P - p) * (u0 - u1);
    }
  }
  float* scrf = (float*)scr;
  scrf[tid] = acc;
  __syncthreads();
  for (int s = 512; s > 0; s >>= 1) {
    if (tid < s) scrf[tid] += scrf[tid + s];
    __syncthreads();
  }
  if (tid == 0) instAcc[seg] = scrf[0];
}

// ---------------- final combine ----------------
__global__ void final_kernel(const float* __restrict__ stats, const float* __restrict__ instAcc,
                             const float* __restrict__ seediAcc, const float* __restrict__ seedbg,
                             float* __restrict__ out) {
  int b = threadIdx.x;
  __shared__ float red[64];
  float lb = 0.f;
  if (b < BATCH) {
    float sv = 0.f, si = 0.f, svar = 0.f, ssd = 0.f;
    for (int n = 0; n < NID; ++n) {
      Params pp = calc_params(stats + (size_t)(b * NID + n) * 8);
      float vf = pp.valid;
      sv += vf;
      si += vf * instAcc[b * NID + n];
      svar += vf * pp.var;
      ssd += vf * seediAcc[b * NID + n];
    }
    float obj = fmaxf(sv, 1.0f);
    lb = si / obj + 10.0f * (svar / obj) + (seedbg[b] + ssd) / (float)HW;
  }
  red[threadIdx.x] = lb;
  __syncthreads();
  for (int s = 32; s > 0; s >>= 1) {
    if (threadIdx.x < s) red[threadIdx.x] += red[threadIdx.x + s];
    __syncthreads();
  }
  if (threadIdx.x == 0) out[0] = red[0] / (float)BATCH;
}

extern "C" void kernel_launch(void* const* d_in, const int* in_sizes, int n_in,
                              void* d_out, int out_size, void* d_ws, size_t ws_size,
                              hipStream_t stream) {
  const float* pred = (const float*)d_in[0];
  const int* inst = (const int*)d_in[1];
  const int* lab = (const int*)d_in[2];
  float* out = (float*)d_out;

  // head (floats): seediAcc[240] | stats[1920] | instAcc[240] | seedbg[16]
  float* wsf = (float*)d_ws;
  float* seediAcc = wsf;
  float* stats = wsf + 240;
  float* instAcc = wsf + 2160;
  float* seedbg = wsf + 2400;
  char* p = (char*)d_ws + HEADB;
  unsigned* exyh = (unsigned*)p;                 p += (size_t)BATCH * HW * 4;         // 16.78 MB
  unsigned* tb8 = (unsigned*)p;                  p += (size_t)BATCH * HW;             // 4.19 MB
  unsigned* sd8 = (unsigned*)p;                  p += (size_t)BATCH * HW;             // 4.19 MB
  unsigned short* partP = (unsigned short*)p;    p += (size_t)NSEG * NSPL * KTOT * 2; // 9.31 MB
  unsigned short* partN = (unsigned short*)p;    p += (size_t)NSEG * NSPL * KTOT * 2; // 9.31 MB
  float* blockpart = (float*)p;                  // 4096*112*4 = 1.84 MB; total ~45.6 MB

  hipMemsetAsync(seediAcc, 0, 240 * sizeof(float), stream);
  pre_kernel<<<PREBLK, 256, 0, stream>>>(pred, inst, lab, blockpart, exyh, tb8, sd8);
  reduce_kernel<<<dim3(NID * 7 + 1, BATCH), 256, 0, stream>>>(blockpart, stats, seedbg);
  hist_kernel<<<NSEG * NSPL, S1T, 0, stream>>>(exyh, tb8, sd8, stats, partP, partN, seediAcc);
  lovasz_kernel<<<NSEG, 1024, 0, stream>>>(partP, partN, stats, instAcc);
  final_kernel<<<1, 64, 0, stream>>>(stats, instAcc, seediAcc, seedbg, out);
}

// Round 7
// 324.196 us; speedup vs baseline: 1.1094x; 1.1094x over previous
//
#include <hip/hip_runtime.h>
#include <hip/hip_fp16.h>
#include <cmath>

#define BATCH 16
#define NID   15
#define NSEG  240
#define HW    262144          // 512*512
#define HEADB 65536
#define NSPL  4               // hist blocks per segment
#define S1T   512             // hist block threads
#define PREBLK 1024           // pre blocks (64 per batch, 4096 px each)
#define PSTRIDE 112           // floats per pre-block partial record (105 stats + 1 bg + pad)

// compact key space for d = exp(-arg) in [0,1]:
//   d >= 2^-8 : fine buckets (float_bits>>15), 2305 keys, ~0.39% relative width
//   d <  2^-8 : exponent-only buckets (float_bits>>23), 119 keys
#define KFINEBASE 30208       // 0x3B800000 >> 15
#define KOVF 119
#define KTOT 2424             // 119 + 2305

__device__ __forceinline__ int keyof(float d) {
  unsigned b = __float_as_uint(d);
  return (b >= 0x3B800000u) ? (int)((b >> 15) - KFINEBASE + KOVF) : (int)(b >> 23);
}
__device__ __forceinline__ void boundsof(int k, float* lo, float* hi) {
  if (k >= KOVF) {
    unsigned u = (unsigned)(k - KOVF + KFINEBASE) << 15;
    *lo = __uint_as_float(u);
    *hi = __uint_as_float(u + 32768u);
  } else {
    *lo = __uint_as_float((unsigned)k << 23);
    *hi = __uint_as_float((unsigned)(k + 1) << 23);
  }
}

// fast transcendentals (ex/ey round to half afterwards; sd quantized to u8 -> error irrelevant)
__device__ __forceinline__ float fast_tanh(float x) {
  float e = __expf(2.0f * x);          // saturates naturally at +-inf
  return 1.0f - 2.0f / (e + 1.0f);
}
__device__ __forceinline__ float fast_sigmoid(float x) {
  return 1.0f / (1.0f + __expf(-x));
}

struct Params { float cx, cy, e0, e1, var, valid, cnt; };
__device__ __forceinline__ Params calc_params(const float* __restrict__ st) {
  Params p;
  float cnt = st[0];
  float safe = fmaxf(cnt, 1.0f);
  p.cx = st[1] / safe;
  p.cy = st[2] / safe;
  float m0 = st[3] / safe, m1 = st[4] / safe;
  float v0 = st[5] - 2.0f * m0 * (m0 * safe) + m0 * m0 * cnt;
  float v1 = st[6] - 2.0f * m1 * (m1 * safe) + m1 * m1 * cnt;
  p.var = (v0 + v1) / (2.0f * safe);
  p.e0 = expf(10.0f * m0);
  p.e1 = expf(10.0f * m1);
  p.valid = (cnt > 0.f) ? 1.f : 0.f;
  p.cnt = cnt;
  return p;
}

// ---------------- pre: pipelined transform + privatized LDS stats + packed records ----------------
__global__ void __launch_bounds__(256)
pre_kernel(const float* __restrict__ pred, const int* __restrict__ inst,
           const int* __restrict__ lab, float* __restrict__ blockpart,
           unsigned* __restrict__ exyh, unsigned* __restrict__ tb8,
           unsigned* __restrict__ sd8) {
  __shared__ float ls[4][8][NID * 7];   // per-wave, 8-way lane-privatized
  __shared__ float lbg[4];
  int tid = threadIdx.x;
  int w = tid >> 6, lane = tid & 63, c8 = lane & 7;
  for (int i = tid; i < 4 * 8 * NID * 7; i += 256) ((float*)ls)[i] = 0.f;
  __syncthreads();
  int gid = blockIdx.x;
  int b = gid >> 6, c = gid & 63;      // 64 blocks per batch, 4096 px per block
  const float* pb = pred + (size_t)b * 5 * HW;
  const int4* ip = (const int4*)(inst + (size_t)b * HW);
  const int4* lp = (const int4*)(lab + (size_t)b * HW);
  float bgacc = 0.f;
  int i4 = c * 1024 + tid;             // float4-group index, iter 0
  float4 v0 = ((const float4*)pb)[i4];
  float4 v1 = ((const float4*)(pb + HW))[i4];
  float4 v2 = ((const float4*)(pb + 2 * HW))[i4];
  float4 v3 = ((const float4*)(pb + 3 * HW))[i4];
  float4 v4 = ((const float4*)(pb + 4 * HW))[i4];
  int4 t4 = ip[i4];
  int4 l4 = lp[i4];
#pragma unroll
  for (int it = 0; it < 4; ++it) {
    float4 n0, n1, n2, n3, n4;
    int4 nt, nl;
    int ni4 = c * 1024 + (it + 1) * 256 + tid;
    if (it < 3) {                      // prefetch next iteration (overlaps compute below)
      n0 = ((const float4*)pb)[ni4];
      n1 = ((const float4*)(pb + HW))[ni4];
      n2 = ((const float4*)(pb + 2 * HW))[ni4];
      n3 = ((const float4*)(pb + 3 * HW))[ni4];
      n4 = ((const float4*)(pb + 4 * HW))[ni4];
      nt = ip[ni4];
      nl = lp[ni4];
    }
    float p0a[4] = {v0.x, v0.y, v0.z, v0.w};
    float p1a[4] = {v1.x, v1.y, v1.z, v1.w};
    float p2a[4] = {v2.x, v2.y, v2.z, v2.w};
    float p3a[4] = {v3.x, v3.y, v3.z, v3.w};
    float p4a[4] = {v4.x, v4.y, v4.z, v4.w};
    int ta[4] = {t4.x, t4.y, t4.z, t4.w};
    int la[4] = {l4.x, l4.y, l4.z, l4.w};
    unsigned eo[4], tpack = 0, spack = 0;
    int px0 = i4 * 4;
#pragma unroll
    for (int k = 0; k < 4; ++k) {
      int px = px0 + k;
      float xm = (float)(px & 511) * (1.0f / 511.0f);
      float ym = (float)(px >> 9) * (1.0f / 511.0f);
      float ex = fast_tanh(p0a[k]) + xm;
      float ey = fast_tanh(p1a[k]) + ym;
      float sd = fast_sigmoid(p4a[k]);
      __half2 h = __floats2half2_rn(ex, ey);
      eo[k] = *reinterpret_cast<unsigned*>(&h);
      int t = ta[k];
      tpack |= ((unsigned)(t & 255)) << (8 * k);
      unsigned sq = (unsigned)(sd * 255.0f + 0.5f);
      spack |= (sq & 255u) << (8 * k);
      if (t >= 1 && t <= NID) {
        float* s = ls[w][c8] + (t - 1) * 7;
        atomicAdd(s + 0, 1.0f);
        atomicAdd(s + 1, ex);
        atomicAdd(s + 2, ey);
        atomicAdd(s + 3, p2a[k]);
        atomicAdd(s + 4, p3a[k]);
        atomicAdd(s + 5, p2a[k] * p2a[k]);
        atomicAdd(s + 6, p3a[k] * p3a[k]);
      }
      if (la[k] == 0) bgacc += sd * sd;
    }
    ((uint4*)exyh)[(size_t)b * (HW / 4) + i4] = make_uint4(eo[0], eo[1], eo[2], eo[3]);
    tb8[(size_t)b * (HW / 4) + i4] = tpack;
    sd8[(size_t)b * (HW / 4) + i4] = spack;
    if (it < 3) {
      v0 = n0; v1 = n1; v2 = n2; v3 = n3; v4 = n4;
      t4 = nt; l4 = nl;
      i4 = ni4;
    }
  }
  for (int off = 32; off > 0; off >>= 1) bgacc += __shfl_down(bgacc, off, 64);
  if (lane == 0) lbg[w] = bgacc;
  __syncthreads();
  float* bp = blockpart + (size_t)gid * PSTRIDE;
  for (int i = tid; i < NID * 7; i += 256) {
    float v = 0.f;
#pragma unroll
    for (int ww = 0; ww < 4; ++ww)
#pragma unroll
      for (int cc = 0; cc < 8; ++cc) v += ls[ww][cc][i];
    bp[i] = v;
  }
  if (tid == 0) bp[NID * 7] = lbg[0] + lbg[1] + lbg[2] + lbg[3];
}

// ---------------- reduce pre partials -> stats, seedbg ----------------
__global__ void reduce_kernel(const float* __restrict__ blockpart, float* __restrict__ stats,
                              float* __restrict__ seedbg) {
  int s = blockIdx.x;       // 0..105
  int b = blockIdx.y;
  int tid = threadIdx.x;    // 64 = blocks per batch
  float v = blockpart[(size_t)(b * 64 + tid) * PSTRIDE + s];
  for (int off = 32; off > 0; off >>= 1) v += __shfl_down(v, off, 64);
  if (tid == 0) {
    if (s < NID * 7) {
      int id = s / 7, st = s % 7;
      stats[(b * NID + id) * 8 + st] = v;
    } else {
      seedbg[b] = v;
    }
  }
}

// ---------------- phase 1: split per-segment LDS histograms from packed records ----------------
__global__ void __launch_bounds__(S1T)
hist_kernel(const unsigned* __restrict__ exyh, const unsigned* __restrict__ tb8,
            const unsigned* __restrict__ sd8, const float* __restrict__ stats,
            unsigned short* __restrict__ partP, unsigned short* __restrict__ partN,
            float* __restrict__ seedi) {
  int bid = blockIdx.x;
  int seg = bid / NSPL, split = bid % NSPL;
  int b = seg / NID, n = seg % NID;
  __shared__ int histP[KTOT];
  __shared__ int histN[KTOT];
  __shared__ float prm[8];
  int tid = threadIdx.x;
  if (tid == 0) {
    Params pp = calc_params(stats + (size_t)seg * 8);
    prm[0] = pp.cx; prm[1] = pp.cy; prm[2] = pp.e0; prm[3] = pp.e1;
    prm[4] = pp.valid;
  }
  for (int k = tid; k < KTOT; k += S1T) { histP[k] = 0; histN[k] = 0; }
  __syncthreads();
  if (prm[4] == 0.f) return;   // invalid segment: partials never read
  float cx = prm[0], cy = prm[1], e0 = prm[2], e1 = prm[3];
  const uint4* ev = (const uint4*)exyh + (size_t)b * (HW / 4);
  const unsigned* tv = tb8 + (size_t)b * (HW / 4);
  const unsigned* sv = sd8 + (size_t)b * (HW / 4);
  int lane = tid & 63;
  int wid = tid >> 6;               // 8 waves
  int swl = (lane * 21) & 63;       // decorrelate bucket keys within a wave
  float sacc = 0.f;
  // 4-px groups: HW/4 = 65536 per batch; per split 16384; per block 32 iters of 512
  int g = split * 16384 + wid * 64 + swl;
  uint4 ee = ev[g];
  unsigned tp = tv[g];
  unsigned sp = sv[g];
  for (int it = 0; it < 32; ++it) {
    uint4 ne; unsigned ntp, nsp;
    int ng = g + 512;
    if (it < 31) { ne = ev[ng]; ntp = tv[ng]; nsp = sv[ng]; }
    unsigned ew[4] = {ee.x, ee.y, ee.z, ee.w};
#pragma unroll
    for (int k = 0; k < 4; ++k) {
      unsigned u = ew[k];
      __half2 h = *reinterpret_cast<__half2*>(&u);
      float2 e = __half22float2(h);
      float dx = e.x - cx;
      float dy = e.y - cy;
      float d = __expf(-(e0 * dx * dx + e1 * dy * dy));
      int key = keyof(d);
      int t = (int)((tp >> (8 * k)) & 255u);
      if (t == n + 1) {
        atomicAdd(&histP[key], 1);
        float sd = (float)((sp >> (8 * k)) & 255u) * (1.0f / 255.0f);
        float df = sd - d;
        sacc += df * df;
      } else {
        atomicAdd(&histN[key], 1);
      }
    }
    if (it < 31) { ee = ne; tp = ntp; sp = nsp; g = ng; }
  }
  for (int off = 32; off > 0; off >>= 1) sacc += __shfl_down(sacc, off, 64);
  if (lane == 0 && sacc != 0.f) atomicAdd(&seedi[seg], sacc);
  __syncthreads();
  size_t pb = (size_t)bid * KTOT;
  for (int k = tid; k < KTOT; k += S1T) {
    partP[pb + k] = (unsigned short)histP[k];
    partN[pb + k] = (unsigned short)histN[k];
  }
}

// ---------------- phase 2+3: combine partials, LDS scans, bucket-sweep Lovasz ----------------
__global__ void __launch_bounds__(1024)
lovasz_kernel(const unsigned short* __restrict__ partP, const unsigned short* __restrict__ partN,
              const float* __restrict__ stats, float* __restrict__ instAcc) {
  __shared__ int histP[KTOT];
  __shared__ int histN[KTOT];
  __shared__ int PreP[KTOT + 1];
  __shared__ int PreN[KTOT + 1];
  __shared__ int scr[1024];
  __shared__ float prm[2];
  int seg = blockIdx.x;
  int tid = threadIdx.x;
  if (tid == 0) {
    Params pp = calc_params(stats + (size_t)seg * 8);
    prm[0] = pp.valid;
    prm[1] = pp.cnt;
  }
  __syncthreads();
  if (prm[0] == 0.f) {
    if (tid == 0) instAcc[seg] = 0.f;
    return;
  }
  int P = (int)prm[1];
  int Nn = HW - P;
  for (int k = tid; k < KTOT; k += 1024) {
    int sp = 0, sn = 0;
#pragma unroll
    for (int s = 0; s < NSPL; ++s) {
      size_t pb = (size_t)(seg * NSPL + s) * KTOT;
      sp += partP[pb + k];
      sn += partN[pb + k];
    }
    histP[k] = sp;
    histN[k] = sn;
  }
  __syncthreads();
  {
    int base = tid * 3;
    int a0 = (base < KTOT) ? histP[base] : 0;
    int a1 = (base + 1 < KTOT) ? histP[base + 1] : 0;
    int a2 = (base + 2 < KTOT) ? histP[base + 2] : 0;
    scr[tid] = a0 + a1 + a2;
    __syncthreads();
    for (int off = 1; off < 1024; off <<= 1) {
      int v = scr[tid];
      int u = (tid >= off) ? scr[tid - off] : 0;
      __syncthreads();
      scr[tid] = v + u;
      __syncthreads();
    }
    int excl = (tid > 0) ? scr[tid - 1] : 0;
    if (base < KTOT) PreP[base] = excl;
    if (base + 1 < KTOT) PreP[base + 1] = excl + a0;
    if (base + 2 < KTOT) PreP[base + 2] = excl + a0 + a1;
    if (tid == 0) PreP[KTOT] = scr[1023];
    __syncthreads();
    a0 = (base < KTOT) ? histN[base] : 0;
    a1 = (base + 1 < KTOT) ? histN[base + 1] : 0;
    a2 = (base + 2 < KTOT) ? histN[base + 2] : 0;
    scr[tid] = a0 + a1 + a2;
    __syncthreads();
    for (int off = 1; off < 1024; off <<= 1) {
      int v = scr[tid];
      int u = (tid >= off) ? scr[tid - off] : 0;
      __syncthreads();
      scr[tid] = v + u;
      __syncthreads();
    }
    excl = (tid > 0) ? scr[tid - 1] : 0;
    if (base < KTOT) PreN[base] = excl;
    if (base + 1 < KTOT) PreN[base + 1] = excl + a0;
    if (base + 2 < KTOT) PreN[base + 2] = excl + a0 + a1;
    if (tid == 0) PreN[KTOT] = scr[1023];
    __syncthreads();
  }
  float acc = 0.f;
  for (int k = tid; k < KTOT; k += 1024) {
    int hp = histP[k], hn = histN[k];
    if ((hp | hn) == 0) continue;
    float lo, hi;
    boundsof(k, &lo, &hi);
    float m = 0.5f * (lo + hi);
    m = fminf(m, __uint_as_float(0x3F7FFFFFu));
    float tv = 1.0f - m;
    int j = keyof(tv);
    float jlo, jhi;
    boundsof(j, &jlo, &jhi);
    float den = jhi - jlo;
    float fr = (den > 0.f) ? (tv - jlo) / den : 0.5f;
    fr = fminf(fmaxf(fr, 0.f), 1.f);
    if (hp) {
      float q = (float)(Nn - PreN[j + 1]) + (1.0f - fr) * (float)histN[j];
      float a = 2.0f - 2.0f * m;
      acc += (float)hp * a / ((float)P + q);
    }
    if (hn) {
      float p = (float)PreP[j] + fr * (float)histP[j];
      int R = Nn - PreN[k + 1];
      float u0 = 1.0f / (float)(P + R);
      float u1 = 1.0f / (float)(P + R + hn);
      acc += (2.0f * m) * ((float)P - p) * (u0 - u1);
    }
  }
  float* scrf = (float*)scr;
  scrf[tid] = acc;
  __syncthreads();
  for (int s = 512; s > 0; s >>= 1) {
    if (tid < s) scrf[tid] += scrf[tid + s];
    __syncthreads();
  }
  if (tid == 0) instAcc[seg] = scrf[0];
}

// ---------------- final combine ----------------
__global__ void final_kernel(const float* __restrict__ stats, const float* __restrict__ instAcc,
                             const float* __restrict__ seediAcc, const float* __restrict__ seedbg,
                             float* __restrict__ out) {
  int b = threadIdx.x;
  __shared__ float red[64];
  float lb = 0.f;
  if (b < BATCH) {
    float sv = 0.f, si = 0.f, svar = 0.f, ssd = 0.f;
    for (int n = 0; n < NID; ++n) {
      Params pp = calc_params(stats + (size_t)(b * NID + n) * 8);
      float vf = pp.valid;
      sv += vf;
      si += vf * instAcc[b * NID + n];
      svar += vf * pp.var;
      ssd += vf * seediAcc[b * NID + n];
    }
    float obj = fmaxf(sv, 1.0f);
    lb = si / obj + 10.0f * (svar / obj) + (seedbg[b] + ssd) / (float)HW;
  }
  red[threadIdx.x] = lb;
  __syncthreads();
  for (int s = 32; s > 0; s >>= 1) {
    if (threadIdx.x < s) red[threadIdx.x] += red[threadIdx.x + s];
    __syncthreads();
  }
  if (threadIdx.x == 0) out[0] = red[0] / (float)BATCH;
}

extern "C" void kernel_launch(void* const* d_in, const int* in_sizes, int n_in,
                              void* d_out, int out_size, void* d_ws, size_t ws_size,
                              hipStream_t stream) {
  const float* pred = (const float*)d_in[0];
  const int* inst = (const int*)d_in[1];
  const int* lab = (const int*)d_in[2];
  float* out = (float*)d_out;

  // head (floats): seediAcc[240] | stats[1920] | instAcc[240] | seedbg[16]
  float* wsf = (float*)d_ws;
  float* seediAcc = wsf;
  float* stats = wsf + 240;
  float* instAcc = wsf + 2160;
  float* seedbg = wsf + 2400;
  char* p = (char*)d_ws + HEADB;
  unsigned* exyh = (unsigned*)p;                 p += (size_t)BATCH * HW * 4;         // 16.78 MB
  unsigned* tb8 = (unsigned*)p;                  p += (size_t)BATCH * HW;             // 4.19 MB
  unsigned* sd8 = (unsigned*)p;                  p += (size_t)BATCH * HW;             // 4.19 MB
  unsigned short* partP = (unsigned short*)p;    p += (size_t)NSEG * NSPL * KTOT * 2; // 4.65 MB
  unsigned short* partN = (unsigned short*)p;    p += (size_t)NSEG * NSPL * KTOT * 2; // 4.65 MB
  float* blockpart = (float*)p;                  // 1024*112*4 = 0.46 MB; total ~35 MB

  hipMemsetAsync(seediAcc, 0, 240 * sizeof(float), stream);
  pre_kernel<<<PREBLK, 256, 0, stream>>>(pred, inst, lab, blockpart, exyh, tb8, sd8);
  reduce_kernel<<<dim3(NID * 7 + 1, BATCH), 64, 0, stream>>>(blockpart, stats, seedbg);
  hist_kernel<<<NSEG * NSPL, S1T, 0, stream>>>(exyh, tb8, sd8, stats, partP, partN, seediAcc);
  lovasz_kernel<<<NSEG, 1024, 0, stream>>>(partP, partN, stats, instAcc);
  final_kernel<<<1, 64, 0, stream>>>(stats, instAcc, seediAcc, seedbg, out);
}